// Round 2
// baseline (165.495 us; speedup 1.0000x reference)
//
#include <hip/hip_runtime.h>
#include <hip/hip_bf16.h>
#include <math.h>
#include <stdint.h>

#define B_N   512
#define D_N   768
#define R_N   128
#define C_NEW 10
#define C_OLD 100
#define C_TOT 110
#define MARGIN_F    5.0f
#define VAR_FLOOR_F 1e-4f
#define BIG_F       1e6f

typedef __bf16 bf16;
typedef __bf16 bf16x4 __attribute__((ext_vector_type(4)));
typedef __bf16 bf16x8 __attribute__((ext_vector_type(8)));
typedef float  f32x4  __attribute__((ext_vector_type(4)));

__device__ __forceinline__ float cleanf(float v) { return isfinite(v) ? v : 0.0f; }

// order-preserving float->uint encode (monotone, handles negatives)
__device__ __forceinline__ unsigned encf(float f) {
    unsigned u = __float_as_uint(f);
    return (u & 0x80000000u) ? ~u : (u | 0x80000000u);
}
__device__ __forceinline__ float decf(unsigned u) {
    return (u & 0x80000000u) ? __uint_as_float(u & 0x7fffffffu) : __uint_as_float(~u);
}

// ---------------------------------------------------------------------------
// prep_T: grid 660 x 256. Transpose tile: basesT[c][r][d] (bf16) from
// bases[c][d][r] (f32) via register 4x4 micro-tiles + XOR-swizzled LDS.
// Block 0 additionally inits ominE (512 x 0xFFFFFFFF) and cnt=0.
// ---------------------------------------------------------------------------
__global__ __launch_bounds__(256)
void prep_T(const float* __restrict__ cur_bases, const float* __restrict__ old_bases,
            bf16* __restrict__ basesT, unsigned* __restrict__ ominE,
            unsigned* __restrict__ cnt)
{
    const int bid = blockIdx.x, t = threadIdx.x;
    if (bid == 0) {
        ominE[t] = 0xFFFFFFFFu;
        ominE[256 + t] = 0xFFFFFFFFu;
        if (t == 0) *cnt = 0u;
    }

    const int dt = bid % 6, c = bid / 6;
    const float* Bc = (c < C_NEW) ? cur_bases + (size_t)c * D_N * R_N
                                  : old_bases + (size_t)(c - C_NEW) * D_N * R_N;
    __shared__ bf16 T[128][128];
    const int d0 = dt * 128;
    const int rg  = t & 31;    // lanes consecutive -> coalesced global loads
    const int dgb = t >> 5;

    #pragma unroll
    for (int i = 0; i < 4; ++i) {
        const int dg = i * 8 + dgb;                          // d-group 0..31
        const float* src = Bc + (size_t)(d0 + dg * 4) * R_N + rg * 4;
        float4 v0 = *(const float4*)(src);
        float4 v1 = *(const float4*)(src + R_N);
        float4 v2 = *(const float4*)(src + 2 * R_N);
        float4 v3 = *(const float4*)(src + 3 * R_N);
        const float* f0 = (const float*)&v0;
        const float* f1 = (const float*)&v1;
        const float* f2 = (const float*)&v2;
        const float* f3 = (const float*)&v3;
        #pragma unroll
        for (int j = 0; j < 4; ++j) {
            const int R = rg * 4 + j;
            const int pc = dg ^ (R & 31);                    // XOR swizzle (8B granule)
            bf16x4 w;
            w[0] = (bf16)f0[j]; w[1] = (bf16)f1[j]; w[2] = (bf16)f2[j]; w[3] = (bf16)f3[j];
            *(bf16x4*)(&T[R][pc * 4]) = w;
        }
    }
    __syncthreads();

    #pragma unroll
    for (int it = 0; it < 16; ++it) {
        const int q = it * 256 + t;
        const int r = q >> 5, u = q & 31;
        const int pc = u ^ (r & 31);
        ushort4 w = *(const ushort4*)(&T[r][pc * 4]);
        *(ushort4*)(basesT + (size_t)c * R_N * D_N + (size_t)r * D_N + d0 + u * 4) = w;
    }
}

// ---------------------------------------------------------------------------
// main_all: grid 448 x 256 (XCD-bijective decode; 8 filler blocks).
// Per block (mt, c):
//   K-loop: stage sA = bf16(clean(z) - mu) (nd2 co-accum in f32),
//           stage sB = basesT tile; MFMA both coeff (diff x B) AND the
//           G = B^T B quadrants (gram fused, G stays in LDS).
//   Epilogue: sG <- accG; sC <- coeff; par/cn; GEMM2 H=coeff*G; qsum; dist.
//   New classes -> gdist[b][c]; old -> atomicMin(ominE[b]).
//   Completion counter: last block runs finalize in-kernel.
// ---------------------------------------------------------------------------
#define PADC 136
#define SM_A   0                       // 128x72 bf16 = 18432
#define SM_B   18432                   // 128x72 bf16 = 18432
#define SM_C   0                       // 128x136 bf16 = 34816 (overlays sA+sB)
#define SM_G   36864                   // 128x136 bf16 = 34816
#define SM_MU  71680                   // 768 f32 = 3072
#define SM_INV 74752                   // 512
#define SM_Q   75264                   // 512
#define SM_PAR 75776                   // 512
#define SM_CN  76288                   // 512
#define SM_ND  76800                   // 512
#define SM_T2  77312                   // 2048 (also finalize scratch)
#define SM_FL  79360                   // 16
#define SM_SZ  79376                   // -> 2 blocks/CU (158752 <= 163840)

__global__ __launch_bounds__(256, 2)
void main_all(const float* __restrict__ z, const bf16* __restrict__ basesT,
              const float* __restrict__ cur_vars, const float* __restrict__ old_vars,
              const float* __restrict__ cur_means, const float* __restrict__ old_means,
              const int* __restrict__ labels, const int* __restrict__ ncid,
              float* __restrict__ gdist, unsigned* __restrict__ ominE,
              unsigned* __restrict__ cnt, float* __restrict__ out)
{
    __shared__ __align__(16) unsigned char smem[SM_SZ];
    bf16*  sA   = (bf16*)(smem + SM_A);
    bf16*  sB   = (bf16*)(smem + SM_B);
    bf16*  sC   = (bf16*)(smem + SM_C);
    bf16*  sG   = (bf16*)(smem + SM_G);
    float* sMu  = (float*)(smem + SM_MU);
    float* sInv = (float*)(smem + SM_INV);
    float* sQ   = (float*)(smem + SM_Q);
    float* sPar = (float*)(smem + SM_PAR);
    float* sCn  = (float*)(smem + SM_CN);
    float* sNd  = (float*)(smem + SM_ND);
    float* sT2  = (float*)(smem + SM_T2);
    unsigned* sFl = (unsigned*)(smem + SM_FL);

    const int tid = threadIdx.x, wave = tid >> 6, lane = tid & 63;
    const int quad = lane >> 4, l15 = lane & 15;
    const int wr = (wave >> 1) * 64, wc = (wave & 1) * 64;

    // XCD-bijective decode: 4 mt-blocks of a class land on one XCD.
    const int fid = blockIdx.x;
    const int c  = (fid & 7) + 8 * (fid >> 5);
    const int mt = (fid >> 3) & 3;

    if (c < C_TOT) {
        const int b0 = mt * 128;
        const float* vars = (c < C_NEW) ? cur_vars + (size_t)c * (R_N + 1)
                                        : old_vars + (size_t)(c - C_NEW) * (R_N + 1);
        const float* mu = (c < C_NEW) ? cur_means + (size_t)c * D_N
                                      : old_means + (size_t)(c - C_NEW) * D_N;

        if (tid < 128) {
            sInv[tid] = 1.0f / fmaxf(vars[tid], VAR_FLOOR_F);
            sQ[tid] = 0.0f;
        }
        for (int i = tid; i < D_N; i += 256) sMu[i] = mu[i];

        f32x4 acc1[4][4], accG[4][4];
        #pragma unroll
        for (int i = 0; i < 4; ++i)
            #pragma unroll
            for (int j = 0; j < 4; ++j) { acc1[i][j] = (f32x4)0.0f; accG[i][j] = (f32x4)0.0f; }
        float nd2p[8];
        #pragma unroll
        for (int p = 0; p < 8; ++p) nd2p[p] = 0.f;

        const int rb = tid >> 4, f4 = tid & 15;
        const float* Az = z + (size_t)b0 * D_N;
        const bf16*  Bb = basesT + (size_t)c * R_N * D_N;

        for (int k0 = 0; k0 < D_N; k0 += 64) {
            __syncthreads();
            // stage sB (bf16 basesT tile, linear)
            #pragma unroll
            for (int p = 0; p < 4; ++p) {
                int q = p * 256 + tid, row = q >> 3, u = q & 7;
                *(uint4*)(sB + row * 72 + u * 8) = *(const uint4*)(Bb + (size_t)row * D_N + k0 + u * 8);
            }
            // stage sA = clean(z) - mu (f32 -> bf16), nd2 co-accum
            {
                float4 m4 = *(const float4*)(sMu + k0 + f4 * 4);
                #pragma unroll
                for (int p = 0; p < 8; ++p) {
                    int row = p * 16 + rb;
                    float4 v = *(const float4*)(Az + (size_t)row * D_N + k0 + f4 * 4);
                    float d0 = cleanf(v.x) - m4.x;
                    float d1 = cleanf(v.y) - m4.y;
                    float d2 = cleanf(v.z) - m4.z;
                    float d3 = cleanf(v.w) - m4.w;
                    nd2p[p] += d0 * d0 + d1 * d1 + d2 * d2 + d3 * d3;
                    bf16x4 w;
                    w[0] = (bf16)d0; w[1] = (bf16)d1; w[2] = (bf16)d2; w[3] = (bf16)d3;
                    *(bf16x4*)(sA + row * 72 + f4 * 4) = w;
                }
            }
            __syncthreads();
            #pragma unroll
            for (int kk = 0; kk < 64; kk += 32) {
                bf16x8 afA[4], bgB[4], afB[4];
                #pragma unroll
                for (int i = 0; i < 4; ++i) afA[i] = *(const bf16x8*)(sA + (wr + 16 * i + l15) * 72 + kk + quad * 8);
                #pragma unroll
                for (int j = 0; j < 4; ++j) bgB[j] = *(const bf16x8*)(sB + (wc + 16 * j + l15) * 72 + kk + quad * 8);
                #pragma unroll
                for (int i = 0; i < 4; ++i) afB[i] = *(const bf16x8*)(sB + (wr + 16 * i + l15) * 72 + kk + quad * 8);
                #pragma unroll
                for (int i = 0; i < 4; ++i)
                    #pragma unroll
                    for (int j = 0; j < 4; ++j) {
                        acc1[i][j] = __builtin_amdgcn_mfma_f32_16x16x32_bf16(afA[i], bgB[j], acc1[i][j], 0, 0, 0);
                        accG[i][j] = __builtin_amdgcn_mfma_f32_16x16x32_bf16(afB[i], bgB[j], accG[i][j], 0, 0, 0);
                    }
            }
        }

        // nd2 per-row: reduce over the 16-lane group sharing a row
        #pragma unroll
        for (int p = 0; p < 8; ++p) {
            float s = nd2p[p];
            s += __shfl_xor(s, 1, 64); s += __shfl_xor(s, 2, 64);
            s += __shfl_xor(s, 4, 64); s += __shfl_xor(s, 8, 64);
            if (l15 == 0) sNd[p * 16 + rb] = s;
        }

        // G -> sG (separate LDS region, no global round-trip)
        #pragma unroll
        for (int i = 0; i < 4; ++i)
            #pragma unroll
            for (int j = 0; j < 4; ++j)
                #pragma unroll
                for (int reg = 0; reg < 4; ++reg)
                    sG[(wr + 16 * i + quad * 4 + reg) * PADC + wc + 16 * j + l15] = (bf16)accG[i][j][reg];
        __syncthreads();   // sA/sB dead everywhere; sG/sNd complete

        // coeff -> sC (overlays sA/sB); no m_c subtraction needed (diff-staged)
        #pragma unroll
        for (int i = 0; i < 4; ++i)
            #pragma unroll
            for (int j = 0; j < 4; ++j)
                #pragma unroll
                for (int reg = 0; reg < 4; ++reg)
                    sC[(wr + 16 * i + quad * 4 + reg) * PADC + wc + 16 * j + l15] = (bf16)acc1[i][j][reg];
        __syncthreads();

        // par / cnorm per row (from bf16 coeff)
        {
            int row = tid >> 1, half = tid & 1;
            float par = 0.f, cn = 0.f;
            #pragma unroll
            for (int m = 0; m < 8; ++m) {
                bf16x8 v = *(const bf16x8*)(sC + row * PADC + half * 64 + m * 8);
                #pragma unroll
                for (int e = 0; e < 8; ++e) {
                    float f = (float)v[e];
                    int col = half * 64 + m * 8 + e;
                    cn  += f * f;
                    par += f * f * sInv[col];
                }
            }
            sT2[tid] = par;
            sT2[256 + tid] = cn;
        }
        __syncthreads();
        if (tid < 128) {
            sPar[tid] = sT2[tid * 2] + sT2[tid * 2 + 1];
            sCn[tid]  = sT2[256 + tid * 2] + sT2[256 + tid * 2 + 1];
        }

        // GEMM2: H = coeff * G (K=128, G from LDS)
        f32x4 acc2[4][4];
        #pragma unroll
        for (int i = 0; i < 4; ++i)
            #pragma unroll
            for (int j = 0; j < 4; ++j) acc2[i][j] = (f32x4)0.0f;
        #pragma unroll
        for (int kc = 0; kc < 128; kc += 32) {
            bf16x8 af[4], bg[4];
            #pragma unroll
            for (int i = 0; i < 4; ++i) af[i] = *(const bf16x8*)(sC + (wr + 16 * i + l15) * PADC + kc + quad * 8);
            #pragma unroll
            for (int j = 0; j < 4; ++j) bg[j] = *(const bf16x8*)(sG + (wc + 16 * j + l15) * PADC + kc + quad * 8);
            #pragma unroll
            for (int i = 0; i < 4; ++i)
                #pragma unroll
                for (int j = 0; j < 4; ++j)
                    acc2[i][j] = __builtin_amdgcn_mfma_f32_16x16x32_bf16(af[i], bg[j], acc2[i][j], 0, 0, 0);
        }

        // qsum[row] = sum_s H[row][s] * coeff[row][s]
        #pragma unroll
        for (int i = 0; i < 4; ++i)
            #pragma unroll
            for (int reg = 0; reg < 4; ++reg) {
                float qp = 0.f;
                #pragma unroll
                for (int j = 0; j < 4; ++j) qp += acc2[i][j][reg] * acc1[i][j][reg];
                qp += __shfl_xor(qp, 1, 64);
                qp += __shfl_xor(qp, 2, 64);
                qp += __shfl_xor(qp, 4, 64);
                qp += __shfl_xor(qp, 8, 64);
                if (l15 == 0) atomicAdd(&sQ[wr + 16 * i + quad * 4 + reg], qp);
            }
        __syncthreads();

        // final dist per row
        if (tid < 128) {
            int b = b0 + tid;
            float res = fmaxf(vars[R_N], VAR_FLOOR_F);
            float dist = (sPar[tid] + (sNd[tid] - 2.0f * sCn[tid] + sQ[tid]) / res) / (float)D_N;
            if (!isfinite(dist)) dist = BIG_F;
            if (c < C_NEW) {
                gdist[(size_t)b * C_NEW + c] = dist;
            } else {
                atomicMin(ominE + b, encf(dist));
            }
        }
    }

    // ---- completion counter; last block finalizes in-kernel ----
    __syncthreads();
    if (tid == 0) {
        __threadfence();                 // release: make our stores visible
        sFl[0] = atomicAdd(cnt, 1u);
    }
    __syncthreads();
    if (sFl[0] == 447u) {
        __threadfence();                 // acquire: invalidate stale cache
        float* accF = sT2;               // reuse scratch
        int* ncidS = (int*)(sT2 + 48);
        if (tid < 40) accF[tid] = 0.f;
        if (tid < C_NEW) ncidS[tid] = ncid[tid];
        __syncthreads();
        #pragma unroll
        for (int rep = 0; rep < 2; ++rep) {
            int b = rep * 256 + tid;
            float mn = decf(ominE[b]);
            int lab = labels[b];
            #pragma unroll
            for (int k = 0; k < C_NEW; ++k) {
                if (lab == ncidS[k]) {
                    int col = min(max(ncidS[k], 0), C_NEW - 1);
                    float ow = gdist[(size_t)b * C_NEW + col];
                    atomicAdd(&accF[k * 4 + 0], 1.0f);
                    atomicAdd(&accF[k * 4 + 1], fmaxf(0.0f, MARGIN_F + ow - mn));
                    atomicAdd(&accF[k * 4 + 2], ow);
                    atomicAdd(&accF[k * 4 + 3], mn);
                }
            }
        }
        __syncthreads();
        if (tid == 0) {
            float total = 0.f, own = 0.f, old = 0.f, nv = 0.f;
            #pragma unroll
            for (int k = 0; k < C_NEW; ++k) {
                float cntk = accF[k * 4 + 0];
                float den = fmaxf(cntk, 1.0f);
                if (cntk > 0.f) {
                    nv += 1.f;
                    total += accF[k * 4 + 1] / den;
                    own   += accF[k * 4 + 2] / den;
                    old   += accF[k * 4 + 3] / den;
                }
            }
            float nvd = fmaxf(nv, 1.0f);
            out[0] = total / nvd;
            out[1] = own / nvd;
            out[2] = old / nvd;
        }
    }
}

// ---------------------------------------------------------------------------
// workspace layout (bytes):
//   gdist  @ 0      : 20480   (512 x 10 f32, new classes only)
//   ominE  @ 20480  : 2048    (512 encoded old-min; init by prep_T blk 0)
//   cnt    @ 22528  : 16      (completion counter; init by prep_T blk 0)
//   basesT @ 22544  : 21626880 -> total ~21.6 MB
// ---------------------------------------------------------------------------
extern "C" void kernel_launch(void* const* d_in, const int* in_sizes, int n_in,
                              void* d_out, int out_size, void* d_ws, size_t ws_size,
                              hipStream_t stream)
{
    const float* features  = (const float*)d_in[0];
    const int*   labels    = (const int*)d_in[1];
    const int*   ncid      = (const int*)d_in[2];
    const float* cur_means = (const float*)d_in[3];
    const float* cur_bases = (const float*)d_in[4];
    const float* cur_vars  = (const float*)d_in[5];
    const float* old_means = (const float*)d_in[6];
    const float* old_bases = (const float*)d_in[7];
    const float* old_vars  = (const float*)d_in[8];

    unsigned char* ws = (unsigned char*)d_ws;
    float*    gdist  = (float*)(ws + 0);
    unsigned* ominE  = (unsigned*)(ws + 20480);
    unsigned* cnt    = (unsigned*)(ws + 22528);
    bf16*     basesT = (bf16*) (ws + 22544);

    prep_T<<<dim3(6 * C_TOT), dim3(256), 0, stream>>>(cur_bases, old_bases,
                                                      basesT, ominE, cnt);
    main_all<<<dim3(448), dim3(256), 0, stream>>>(features, basesT,
                                                  cur_vars, old_vars,
                                                  cur_means, old_means,
                                                  labels, ncid,
                                                  gdist, ominE, cnt, (float*)d_out);
}